// Round 3
// baseline (530.266 us; speedup 1.0000x reference)
//
#include <hip/hip_runtime.h>
#include <hip/hip_bf16.h>

typedef unsigned short u16;
typedef float v4f __attribute__((ext_vector_type(4)));
typedef __bf16 v8bf __attribute__((ext_vector_type(8)));
typedef unsigned short v4u __attribute__((ext_vector_type(4)));
typedef unsigned short v8u __attribute__((ext_vector_type(8)));

#define EMB 1024
#define TOK 4096
#define LSEQ 2048
#define NBATCH 2
#define SCALING 0.015625f
#define LN_EPS 1e-5f

__device__ __forceinline__ float bf2f(u16 u) {
  unsigned int i = ((unsigned int)u) << 16;
  return __builtin_bit_cast(float, i);
}
__device__ __forceinline__ u16 f2bf(float f) {
  __hip_bfloat16 h = __float2bfloat16(f);  // RNE
  return __builtin_bit_cast(u16, h);
}
__device__ __forceinline__ v8bf load8(const u16* p) {
  return *reinterpret_cast<const v8bf*>(p);
}
__device__ __forceinline__ v4f mfma16(v8bf a, v8bf b, v4f c) {
  return __builtin_amdgcn_mfma_f32_16x16x32_bf16(a, b, c, 0, 0, 0);
}
// async global->LDS, 16B/lane; LDS dest = wave-uniform base + lane*16
__device__ __forceinline__ void gload16(const u16* g, u16* l) {
  __builtin_amdgcn_global_load_lds(
      (const __attribute__((address_space(1))) void*)g,
      (__attribute__((address_space(3))) void*)l, 16, 0, 0);
}
// fast GELU (tanh form, ~9 VALU ops, no divergence): max |err| ~3e-4
__device__ __forceinline__ float gelu_fast(float v) {
  float u = v * (0.7978845608f + 0.0356774081f * v * v);
  return v / (1.0f + __expf(-2.0f * u));
}

// ---------------- fp32 -> bf16 weight conversion -------------------------
__global__ __launch_bounds__(256) void cvt_kernel(
    const float* __restrict__ in, u16* __restrict__ out) {
  size_t i = ((size_t)blockIdx.x * 256 + threadIdx.x) * 8;
  v4f a = *reinterpret_cast<const v4f*>(in + i);
  v4f b = *reinterpret_cast<const v4f*>(in + i + 4);
  v8u r;
#pragma unroll
  for (int j = 0; j < 4; j++) { r[j] = f2bf(a[j]); r[4 + j] = f2bf(b[j]); }
  *reinterpret_cast<v8u*>(out + i) = r;
}

// ---------------- split-K reduce: out += p0(bf16) ------------------------
// chunk-1 partial (incl. bias + x2 residual) already sits fp32 in out.
__global__ __launch_bounds__(256) void addred_kernel(
    float* __restrict__ out, const u16* __restrict__ p0) {
  size_t i = ((size_t)blockIdx.x * 256 + threadIdx.x) * 8;
  v4f a0 = *reinterpret_cast<const v4f*>(out + i);
  v4f a1 = *reinterpret_cast<const v4f*>(out + i + 4);
  v8u pp = *reinterpret_cast<const v8u*>(p0 + i);
#pragma unroll
  for (int j = 0; j < 4; j++) {
    a0[j] += bf2f(pp[j]);
    a1[j] += bf2f(pp[4 + j]);
  }
  *reinterpret_cast<v4f*>(out + i) = a0;
  *reinterpret_cast<v4f*>(out + i + 4) = a1;
}

// ---------------- LayerNorm: MODE 0 bf16-in, MODE 1 fp32-in -> bf16 out --
template <int MODE>
__global__ __launch_bounds__(256) void ln_kernel(
    const void* __restrict__ xin, const float* __restrict__ w,
    const float* __restrict__ b, u16* __restrict__ y) {
  int t = blockIdx.x, tid = threadIdx.x;
  float v[4];
  if (MODE == 0) {
    v4u raw = *reinterpret_cast<const v4u*>((const u16*)xin + (size_t)t * EMB + tid * 4);
#pragma unroll
    for (int j = 0; j < 4; j++) v[j] = bf2f(raw[j]);
  } else {
    v4f raw = *reinterpret_cast<const v4f*>((const float*)xin + (size_t)t * EMB + tid * 4);
#pragma unroll
    for (int j = 0; j < 4; j++) v[j] = raw[j];
  }
  float s = v[0] + v[1] + v[2] + v[3];
  float ss = v[0] * v[0] + v[1] * v[1] + v[2] * v[2] + v[3] * v[3];
#pragma unroll
  for (int off = 32; off >= 1; off >>= 1) {
    s += __shfl_xor(s, off);
    ss += __shfl_xor(ss, off);
  }
  __shared__ float sm[4], sq[4];
  if ((tid & 63) == 0) { sm[tid >> 6] = s; sq[tid >> 6] = ss; }
  __syncthreads();
  s = sm[0] + sm[1] + sm[2] + sm[3];
  ss = sq[0] + sq[1] + sq[2] + sq[3];
  float mu = s * (1.0f / EMB);
  float var = ss * (1.0f / EMB) - mu * mu;
  float rstd = rsqrtf(var + LN_EPS);
  v4f wv = *reinterpret_cast<const v4f*>(w + tid * 4);
  v4f bv = *reinterpret_cast<const v4f*>(b + tid * 4);
  v4u out;
#pragma unroll
  for (int j = 0; j < 4; j++) out[j] = f2bf((v[j] - mu) * rstd * wv[j] + bv[j]);
  *reinterpret_cast<v4u*>(y + (size_t)t * EMB + tid * 4) = out;
}

// ---------------- small GEMM engine (256 thr, <64,128>): out GEMM only ---
// mode 1: out_bf = bf16(res_f32 + v)
template <int BM, int BN>
__global__ __launch_bounds__(256) void gemm_db_kernel(
    const u16* __restrict__ A, const u16* __restrict__ W,
    const float* __restrict__ bias, int K, int Nout, int mode,
    u16* __restrict__ out_bf, float* __restrict__ out_f,
    const float* __restrict__ res_f32, const u16* __restrict__ res_bf) {
  constexpr int NJ = BM * BN / 4096;   // col fragments per wave
  constexpr int CWV = 4 / (BM / 64);   // col-waves
  __shared__ alignas(16) u16 lA[2][BM * 32];  // [buf][seg][row][8]
  __shared__ alignas(16) u16 lB[2][BN * 32];  // [buf][seg][col][8]

  int tid = threadIdx.x;
  int lane = tid & 63, wid = tid >> 6;
  int quad = lane >> 4, l16 = lane & 15;
  int row0 = blockIdx.x * BM;
  int col0 = blockIdx.y * BN;
  int rw = (wid / CWV) * 64;
  int cw = (wid % CWV) * (BN / CWV);

  v4f zero = {0.f, 0.f, 0.f, 0.f};
  v4f acc[4][NJ];
#pragma unroll
  for (int i = 0; i < 4; i++)
#pragma unroll
    for (int j = 0; j < NJ; j++) acc[i][j] = zero;

  int wbase8 = (tid & 192) * 8;  // wave-uniform LDS slot base (u16 units)

  auto stage = [&](int buf, int k0) {
    const u16* Ab = A + (size_t)row0 * K + k0;
    const u16* Wb = W + (size_t)col0 * K + k0;
#pragma unroll
    for (int n = 0; n < BM / 64; n++) {
      int slot = n * 256 + tid;
      int seg = slot / BM, r = slot & (BM - 1);
      gload16(Ab + (size_t)r * K + seg * 8, &lA[buf][n * 2048 + wbase8]);
    }
#pragma unroll
    for (int n = 0; n < BN / 64; n++) {
      int slot = n * 256 + tid;
      int seg = slot / BN, r = slot & (BN - 1);
      gload16(Wb + (size_t)r * K + seg * 8, &lB[buf][n * 2048 + wbase8]);
    }
  };

  stage(0, 0);
  int buf = 0;
  for (int k0 = 0; k0 < K; k0 += 32) {
    __syncthreads();
    if (k0 + 32 < K) stage(buf ^ 1, k0 + 32);

    v8bf af[4], bfr[NJ];
#pragma unroll
    for (int i = 0; i < 4; i++)
      af[i] = load8(&lA[buf][(quad * BM + rw + i * 16 + l16) * 8]);
#pragma unroll
    for (int j = 0; j < NJ; j++)
      bfr[j] = load8(&lB[buf][(quad * BN + cw + j * 16 + l16) * 8]);
#pragma unroll
    for (int i = 0; i < 4; i++)
#pragma unroll
      for (int j = 0; j < NJ; j++)
        acc[i][j] = mfma16(af[i], bfr[j], acc[i][j]);
    buf ^= 1;
  }

#pragma unroll
  for (int i = 0; i < 4; i++) {
    int rbase = row0 + rw + i * 16 + quad * 4;
#pragma unroll
    for (int j = 0; j < NJ; j++) {
      int c = col0 + cw + j * 16 + l16;
      float bv = bias[c];
#pragma unroll
      for (int r = 0; r < 4; r++) {
        int tok = rbase + r;
        float v = acc[i][j][r] + bv;
        size_t idx = (size_t)tok * Nout + c;
        if (mode == 1) {
          out_bf[idx] = f2bf(res_f32[idx] + v);
        } else if (mode == 3) {
          out_f[idx] = bf2f(res_bf[idx]) + v;
        }
      }
    }
  }
}

// ---------------- big-tile GEMM engine (512 thr, 8 waves 2x4) ------------
// R12: GEMMs are staging-BW bound (~5-6.7 TB/s L2->LDS; R10 occupancy-
// doubling was neutral, R11/R12 staged-byte cuts tracked duration).
// Time ~= 2*M*N*K*(1/BM+1/BN) / 6 TB/s  =>  maximize tile.  256^2 doubles
// AI over 128^2 (128 vs 64 FLOP/staged-byte); learn-loop m248v2 measured
// 2-phase 256^2 @K=1024 = 666 TF refcheck'd (~2x our 128^2's 318 TF).
// Same 2-barrier double-buffered structure, 512 threads, wave tile
// BM/2 x BN/4 (NI=BM/32 x NJ=BN/64 fragments), VGPR ~200 (<=256 => 2
// waves/SIMD, 1 block/CU).
// mode 2: out_bf = gelu_fast(v)   mode 4: qkv head-major scatter
// mode 5: split-K=2 over blockIdx.z. z==0 -> bf16 raw partial in out_bf,
//         z==1 -> fp32 (v+bias+res_bf) in out_f; addred_kernel adds p0.
template <int BM, int BN>
__global__ __launch_bounds__(512, 2) void gemm_big_kernel(
    const u16* __restrict__ A, const u16* __restrict__ W,
    const float* __restrict__ bias, int K, int Nout, int mode,
    u16* __restrict__ out_bf, float* __restrict__ out_f,
    const u16* __restrict__ res_bf) {
  constexpr int NI = BM / 32;   // row fragments per wave (2 row-waves)
  constexpr int NJ = BN / 64;   // col fragments per wave (4 col-waves)
  __shared__ alignas(16) u16 lA[2][BM * 32];  // [buf][seg][row][8]
  __shared__ alignas(16) u16 lB[2][BN * 32];  // [buf][seg][col][8]

  int tid = threadIdx.x;
  int lane = tid & 63, wid = tid >> 6;
  int quad = lane >> 4, l16 = lane & 15;
  int row0 = blockIdx.x * BM;
  int col0 = blockIdx.y * BN;
  int rw = (wid >> 2) * (BM / 2);
  int cw = (wid & 3) * (BN / 4);

  int kbeg = 0, kend = K;
  if (mode == 5) {
    int half = K >> 1;
    kbeg = blockIdx.z * half;
    kend = kbeg + half;
  }

  v4f zero = {0.f, 0.f, 0.f, 0.f};
  v4f acc[NI][NJ];
#pragma unroll
  for (int i = 0; i < NI; i++)
#pragma unroll
    for (int j = 0; j < NJ; j++) acc[i][j] = zero;

  int wbase8 = (tid & 448) * 8;  // wave-uniform LDS slot base (u16 units)

  auto stage = [&](int buf, int k0) {
    const u16* Ab = A + (size_t)row0 * K + k0;
    const u16* Wb = W + (size_t)col0 * K + k0;
    // A: BM*4 slots of 16B, [seg][row][8]; 512 slots per n-group
#pragma unroll
    for (int n = 0; n < BM / 128; n++) {
      int slot = n * 512 + tid;
      int seg = slot / BM, r = slot & (BM - 1);
      gload16(Ab + (size_t)r * K + seg * 8, &lA[buf][n * 4096 + wbase8]);
    }
#pragma unroll
    for (int n = 0; n < BN / 128; n++) {
      int slot = n * 512 + tid;
      int seg = slot / BN, r = slot & (BN - 1);
      gload16(Wb + (size_t)r * K + seg * 8, &lB[buf][n * 4096 + wbase8]);
    }
  };

  stage(0, kbeg);
  int buf = 0;
  for (int k0 = kbeg; k0 < kend; k0 += 32) {
    __syncthreads();  // prefetch into buf landed; buf^1 free to overwrite
    if (k0 + 32 < kend) stage(buf ^ 1, k0 + 32);

    v8bf af[NI], bfr[NJ];
#pragma unroll
    for (int i = 0; i < NI; i++)
      af[i] = load8(&lA[buf][(quad * BM + rw + i * 16 + l16) * 8]);
#pragma unroll
    for (int j = 0; j < NJ; j++)
      bfr[j] = load8(&lB[buf][(quad * BN + cw + j * 16 + l16) * 8]);
#pragma unroll
    for (int i = 0; i < NI; i++)
#pragma unroll
      for (int j = 0; j < NJ; j++)
        acc[i][j] = mfma16(af[i], bfr[j], acc[i][j]);
    buf ^= 1;
  }

#pragma unroll
  for (int i = 0; i < NI; i++) {
    int rbase = row0 + rw + i * 16 + quad * 4;
#pragma unroll
    for (int j = 0; j < NJ; j++) {
      int c = col0 + cw + j * 16 + l16;
      float bv = bias[c];
#pragma unroll
      for (int r = 0; r < 4; r++) {
        int tok = rbase + r;
        float raw = acc[i][j][r];
        float v = raw + bv;
        if (mode == 4) {
          int region = c >> 10;  // 0=q,1=k,2=v
          int cc = c & 1023;
          int hh = cc >> 6, dd = cc & 63;
          int l = tok >> 1, nn = tok & 1;
          size_t hb = (size_t)(nn * 16 + hh);
          if (region == 0) {
            out_bf[(hb * LSEQ + l) * 64 + dd] = f2bf(v * SCALING);
          } else if (region == 1) {
            out_bf[4194304 + (hb * LSEQ + l) * 64 + dd] = f2bf(v);
          } else {
            out_bf[8388608 + (hb * 64 + dd) * LSEQ + l] = f2bf(v);
          }
        } else {
          size_t idx = (size_t)tok * Nout + c;
          if (mode == 2) {
            out_bf[idx] = f2bf(gelu_fast(v));
          } else {  // mode 5: split-K partials
            if (blockIdx.z == 0) {
              out_bf[idx] = f2bf(raw);                  // chunk-0 raw partial
            } else {
              out_f[idx] = v + bf2f(res_bf[idx]);       // chunk-1 + bias + x2
            }
          }
        }
      }
    }
  }
}

// ---------------- Flash attention (no-max softmax, swizzled LDS) ---------
// Inputs head-major: q,k (n,h,l,d) [q pre-scaled], vt (n,h,d,l).
__global__ __launch_bounds__(256) void flash_kernel(
    const u16* __restrict__ qb, const u16* __restrict__ kb,
    const u16* __restrict__ vtb, u16* __restrict__ o) {
  int tid = threadIdx.x;
  int lane = tid & 63, wid = tid >> 6;
  int quad = lane >> 4, l16 = lane & 15;
  int qt = blockIdx.x;
  int nh = blockIdx.y;
  int n = nh >> 4, h = nh & 15;

  __shared__ alignas(16) u16 lK[4096];
  __shared__ alignas(16) u16 lV[4096];
  __shared__ alignas(16) u16 pl[128][72];

  const u16* khead = kb + (size_t)nh * (LSEQ * 64);
  const u16* vhead = vtb + (size_t)nh * (64 * LSEQ);

  v4f zero = {0.f, 0.f, 0.f, 0.f};
  v4f acc_o[2][4];
  float lsum[2][4];
#pragma unroll
  for (int i = 0; i < 2; i++) {
#pragma unroll
    for (int r = 0; r < 4; r++) lsum[i][r] = 0.f;
#pragma unroll
    for (int jd = 0; jd < 4; jd++) acc_o[i][jd] = zero;
  }

  v8bf qf[2][2];
#pragma unroll
  for (int i = 0; i < 2; i++) {
    int lq = qt * 128 + wid * 32 + i * 16 + l16;
#pragma unroll
    for (int kk = 0; kk < 2; kk++)
      qf[i][kk] = load8(qb + ((size_t)nh * LSEQ + lq) * 64 + kk * 32 + quad * 8);
  }

  int swl = l16 & 7;
  int srow = tid >> 3;
  int sseg0 = tid & 7;
  int lbase = (tid & 192) * 8;

  for (int s0 = 0; s0 < LSEQ; s0 += 64) {
#pragma unroll
    for (int p = 0; p < 2; p++) {
      int row = p * 32 + srow;
      int seg = sseg0 ^ (row & 7);
      gload16(khead + (size_t)(s0 + row) * 64 + seg * 8, &lK[p * 2048 + lbase]);
      gload16(vhead + (size_t)row * LSEQ + s0 + seg * 8, &lV[p * 2048 + lbase]);
    }
    __syncthreads();

    v4f sacc[2][4];
#pragma unroll
    for (int i = 0; i < 2; i++)
#pragma unroll
      for (int j = 0; j < 4; j++) sacc[i][j] = zero;
#pragma unroll
    for (int kk = 0; kk < 2; kk++) {
      v8bf kf[4];
#pragma unroll
      for (int j = 0; j < 4; j++) {
        int rl = j * 16 + l16;
        kf[j] = load8(&lK[((rl << 3) + (((kk << 2) + quad) ^ swl)) << 3]);
      }
#pragma unroll
      for (int i = 0; i < 2; i++)
#pragma unroll
        for (int j = 0; j < 4; j++)
          sacc[i][j] = mfma16(qf[i][kk], kf[j], sacc[i][j]);
    }

#pragma unroll
    for (int i = 0; i < 2; i++) {
#pragma unroll
      for (int r = 0; r < 4; r++) {
        float ps = 0.f;
#pragma unroll
        for (int j = 0; j < 4; j++) {
          float p = __expf(fminf(sacc[i][j][r], 60.f));
          ps += p;
          pl[wid * 32 + i * 16 + quad * 4 + r][j * 16 + l16] = f2bf(p);
        }
        lsum[i][r] += ps;
      }
    }

#pragma unroll
    for (int kk = 0; kk < 2; kk++) {
      v8bf pf[2], vf[4];
#pragma unroll
      for (int i = 0; i < 2; i++)
        pf[i] = load8(&pl[wid * 32 + i * 16 + l16][kk * 32 + quad * 8]);
#pragma unroll
      for (int jd = 0; jd < 4; jd++) {
        int dl = jd * 16 + l16;
        vf[jd] = load8(&lV[((dl << 3) + (((kk << 2) + quad) ^ swl)) << 3]);
      }
#pragma unroll
      for (int i = 0; i < 2; i++)
#pragma unroll
        for (int jd = 0; jd < 4; jd++)
          acc_o[i][jd] = mfma16(pf[i], vf[jd], acc_o[i][jd]);
    }
    __syncthreads();
  }

#pragma unroll
  for (int i = 0; i < 2; i++) {
#pragma unroll
    for (int r = 0; r < 4; r++) {
      float s = lsum[i][r];
#pragma unroll
      for (int off = 1; off < 16; off <<= 1) s += __shfl_xor(s, off);
      float inv = 1.0f / s;
      int lq = qt * 128 + wid * 32 + i * 16 + quad * 4 + r;
      size_t t = (size_t)lq * NBATCH + n;
#pragma unroll
      for (int jd = 0; jd < 4; jd++)
        o[t * EMB + h * 64 + jd * 16 + l16] = f2bf(acc_o[i][jd][r] * inv);
    }
  }
}

// ---------------- launcher ----------------
extern "C" void kernel_launch(void* const* d_in, const int* in_sizes, int n_in,
                              void* d_out, int out_size, void* d_ws,
                              size_t ws_size, hipStream_t stream) {
  const float* x = (const float*)d_in[0];
  const float* ln1_w = (const float*)d_in[1];
  const float* ln1_b = (const float*)d_in[2];
  const float* in_proj_w = (const float*)d_in[3];
  const float* in_proj_b = (const float*)d_in[4];
  const float* out_w = (const float*)d_in[5];
  const float* out_b = (const float*)d_in[6];
  const float* ln2_w = (const float*)d_in[7];
  const float* ln2_b = (const float*)d_in[8];
  const float* fc_w = (const float*)d_in[9];
  const float* fc_b = (const float*)d_in[10];
  const float* proj_w = (const float*)d_in[11];
  const float* proj_b = (const float*)d_in[12];
  float* out = (float*)d_out;

  char* ws = (char*)d_ws;
  // wbuf [0,8) ; y/o/h [8,40) ; qkv head-major [16,40) ; x2 bf16 [40,48) ;
  // z [48,56).  56 MB peak (known-good budget).
  u16* wbuf = (u16*)(ws + 0);
  u16* y = (u16*)(ws + 8388608);
  u16* qkvh = (u16*)(ws + 16777216);
  u16* o = (u16*)(ws + 8388608);
  u16* hbuf = (u16*)(ws + 8388608);
  u16* x2 = (u16*)(ws + 41943040);
  u16* z = (u16*)(ws + 50331648);

  u16* qb = qkvh;
  u16* kb = qkvh + 4194304;
  u16* vtb = qkvh + 8388608;

  // 1. ln1(x) -> y
  ln_kernel<1><<<TOK, 256, 0, stream>>>((const void*)x, ln1_w, ln1_b, y);
  // 2. qkv = y @ in_proj^T + b, head-major scatter (q scaled).
  //    R12: 256^2 tile -> staged 384->192 MB. Grid (16,12).
  cvt_kernel<<<1536, 256, 0, stream>>>(in_proj_w, wbuf);
  gemm_big_kernel<256, 256><<<dim3(16, 12), 512, 0, stream>>>(
      y, wbuf, in_proj_b, EMB, 3 * EMB, 4, qkvh, nullptr, nullptr);
  // 3. attention -> o
  flash_kernel<<<dim3(16, 32), 256, 0, stream>>>(qb, kb, vtb, o);
  // 4. x2 = bf16(x + o @ out_w^T + out_b). Small GEMM, unchanged.
  cvt_kernel<<<512, 256, 0, stream>>>(out_w, wbuf);
  gemm_db_kernel<64, 128><<<dim3(64, 8), 256, 0, stream>>>(
      o, wbuf, out_b, EMB, EMB, 1, x2, nullptr, x, nullptr);
  // 5. ln2(x2) -> z
  ln_kernel<0><<<TOK, 256, 0, stream>>>((const void*)x2, ln2_w, ln2_b, z);
  // 6. h = gelu_fast(z @ fc_w^T + fc_b). R12: 256^2, staged 512->256 MB.
  //    Grid (16,16) = 1 blk/CU exactly.
  cvt_kernel<<<2048, 256, 0, stream>>>(fc_w, wbuf);
  gemm_big_kernel<256, 256><<<dim3(16, 16), 512, 0, stream>>>(
      z, wbuf, fc_b, EMB, 4 * EMB, 2, hbuf, nullptr, nullptr);
  // 7. out = x2 + h @ proj_w^T + proj_b. R12: 256x128 sk2 -> staged
  //    512->403 MB, AI 85 FLOP/B, 256 blocks. Chunk0 -> bf16 partial in z;
  //    chunk1 (+bias+x2) -> fp32 d_out; addred does out += p0.
  cvt_kernel<<<2048, 256, 0, stream>>>(proj_w, wbuf);
  gemm_big_kernel<256, 128><<<dim3(16, 8, 2), 512, 0, stream>>>(
      hbuf, wbuf, proj_b, 4 * EMB, EMB, 5, z, out, x2);
  addred_kernel<<<2048, 256, 0, stream>>>(out, z);
}

// Round 4
// 527.122 us; speedup vs baseline: 1.0060x; 1.0060x over previous
//
#include <hip/hip_runtime.h>
#include <hip/hip_bf16.h>

typedef unsigned short u16;
typedef float v4f __attribute__((ext_vector_type(4)));
typedef __bf16 v8bf __attribute__((ext_vector_type(8)));
typedef unsigned short v4u __attribute__((ext_vector_type(4)));
typedef unsigned short v8u __attribute__((ext_vector_type(8)));

#define EMB 1024
#define TOK 4096
#define LSEQ 2048
#define NBATCH 2
#define SCALING 0.015625f
#define LN_EPS 1e-5f

__device__ __forceinline__ float bf2f(u16 u) {
  unsigned int i = ((unsigned int)u) << 16;
  return __builtin_bit_cast(float, i);
}
__device__ __forceinline__ u16 f2bf(float f) {
  __hip_bfloat16 h = __float2bfloat16(f);  // RNE
  return __builtin_bit_cast(u16, h);
}
__device__ __forceinline__ v8bf load8(const u16* p) {
  return *reinterpret_cast<const v8bf*>(p);
}
__device__ __forceinline__ v4f mfma16(v8bf a, v8bf b, v4f c) {
  return __builtin_amdgcn_mfma_f32_16x16x32_bf16(a, b, c, 0, 0, 0);
}
// async global->LDS, 16B/lane; LDS dest = wave-uniform base + lane*16
__device__ __forceinline__ void gload16(const u16* g, u16* l) {
  __builtin_amdgcn_global_load_lds(
      (const __attribute__((address_space(1))) void*)g,
      (__attribute__((address_space(3))) void*)l, 16, 0, 0);
}
// counted vmcnt wait: allow N loads to remain in flight (T4; literal must
// be compile-time, hence template dispatch)
template <int N>
__device__ __forceinline__ void waitcnt_vm() {
  if constexpr (N == 0) asm volatile("s_waitcnt vmcnt(0)" ::: "memory");
  else if constexpr (N == 2) asm volatile("s_waitcnt vmcnt(2)" ::: "memory");
  else if constexpr (N == 3) asm volatile("s_waitcnt vmcnt(3)" ::: "memory");
  else if constexpr (N == 4) asm volatile("s_waitcnt vmcnt(4)" ::: "memory");
  else if constexpr (N == 6) asm volatile("s_waitcnt vmcnt(6)" ::: "memory");
  else if constexpr (N == 8) asm volatile("s_waitcnt vmcnt(8)" ::: "memory");
}
// fast GELU (tanh form, ~9 VALU ops, no divergence): max |err| ~3e-4
__device__ __forceinline__ float gelu_fast(float v) {
  float u = v * (0.7978845608f + 0.0356774081f * v * v);
  return v / (1.0f + __expf(-2.0f * u));
}

// ---------------- fp32 -> bf16 weight conversion -------------------------
__global__ __launch_bounds__(256) void cvt_kernel(
    const float* __restrict__ in, u16* __restrict__ out) {
  size_t i = ((size_t)blockIdx.x * 256 + threadIdx.x) * 8;
  v4f a = *reinterpret_cast<const v4f*>(in + i);
  v4f b = *reinterpret_cast<const v4f*>(in + i + 4);
  v8u r;
#pragma unroll
  for (int j = 0; j < 4; j++) { r[j] = f2bf(a[j]); r[4 + j] = f2bf(b[j]); }
  *reinterpret_cast<v8u*>(out + i) = r;
}

// ---------------- split-K reduce: out += p0(bf16) ------------------------
__global__ __launch_bounds__(256) void addred_kernel(
    float* __restrict__ out, const u16* __restrict__ p0) {
  size_t i = ((size_t)blockIdx.x * 256 + threadIdx.x) * 8;
  v4f a0 = *reinterpret_cast<const v4f*>(out + i);
  v4f a1 = *reinterpret_cast<const v4f*>(out + i + 4);
  v8u pp = *reinterpret_cast<const v8u*>(p0 + i);
#pragma unroll
  for (int j = 0; j < 4; j++) {
    a0[j] += bf2f(pp[j]);
    a1[j] += bf2f(pp[4 + j]);
  }
  *reinterpret_cast<v4f*>(out + i) = a0;
  *reinterpret_cast<v4f*>(out + i + 4) = a1;
}

// ---------------- LayerNorm: MODE 0 bf16-in, MODE 1 fp32-in -> bf16 out --
template <int MODE>
__global__ __launch_bounds__(256) void ln_kernel(
    const void* __restrict__ xin, const float* __restrict__ w,
    const float* __restrict__ b, u16* __restrict__ y) {
  int t = blockIdx.x, tid = threadIdx.x;
  float v[4];
  if (MODE == 0) {
    v4u raw = *reinterpret_cast<const v4u*>((const u16*)xin + (size_t)t * EMB + tid * 4);
#pragma unroll
    for (int j = 0; j < 4; j++) v[j] = bf2f(raw[j]);
  } else {
    v4f raw = *reinterpret_cast<const v4f*>((const float*)xin + (size_t)t * EMB + tid * 4);
#pragma unroll
    for (int j = 0; j < 4; j++) v[j] = raw[j];
  }
  float s = v[0] + v[1] + v[2] + v[3];
  float ss = v[0] * v[0] + v[1] * v[1] + v[2] * v[2] + v[3] * v[3];
#pragma unroll
  for (int off = 32; off >= 1; off >>= 1) {
    s += __shfl_xor(s, off);
    ss += __shfl_xor(ss, off);
  }
  __shared__ float sm[4], sq[4];
  if ((tid & 63) == 0) { sm[tid >> 6] = s; sq[tid >> 6] = ss; }
  __syncthreads();
  s = sm[0] + sm[1] + sm[2] + sm[3];
  ss = sq[0] + sq[1] + sq[2] + sq[3];
  float mu = s * (1.0f / EMB);
  float var = ss * (1.0f / EMB) - mu * mu;
  float rstd = rsqrtf(var + LN_EPS);
  v4f wv = *reinterpret_cast<const v4f*>(w + tid * 4);
  v4f bv = *reinterpret_cast<const v4f*>(b + tid * 4);
  v4u out;
#pragma unroll
  for (int j = 0; j < 4; j++) out[j] = f2bf((v[j] - mu) * rstd * wv[j] + bv[j]);
  *reinterpret_cast<v4u*>(y + (size_t)t * EMB + tid * 4) = out;
}

// ---------------- small GEMM engine (256 thr, <64,128>): out GEMM only ---
// mode 1: out_bf = bf16(res_f32 + v)
template <int BM, int BN>
__global__ __launch_bounds__(256) void gemm_db_kernel(
    const u16* __restrict__ A, const u16* __restrict__ W,
    const float* __restrict__ bias, int K, int Nout, int mode,
    u16* __restrict__ out_bf, float* __restrict__ out_f,
    const float* __restrict__ res_f32, const u16* __restrict__ res_bf) {
  constexpr int NJ = BM * BN / 4096;   // col fragments per wave
  constexpr int CWV = 4 / (BM / 64);   // col-waves
  __shared__ alignas(16) u16 lA[2][BM * 32];  // [buf][seg][row][8]
  __shared__ alignas(16) u16 lB[2][BN * 32];  // [buf][seg][col][8]

  int tid = threadIdx.x;
  int lane = tid & 63, wid = tid >> 6;
  int quad = lane >> 4, l16 = lane & 15;
  int row0 = blockIdx.x * BM;
  int col0 = blockIdx.y * BN;
  int rw = (wid / CWV) * 64;
  int cw = (wid % CWV) * (BN / CWV);

  v4f zero = {0.f, 0.f, 0.f, 0.f};
  v4f acc[4][NJ];
#pragma unroll
  for (int i = 0; i < 4; i++)
#pragma unroll
    for (int j = 0; j < NJ; j++) acc[i][j] = zero;

  int wbase8 = (tid & 192) * 8;  // wave-uniform LDS slot base (u16 units)

  auto stage = [&](int buf, int k0) {
    const u16* Ab = A + (size_t)row0 * K + k0;
    const u16* Wb = W + (size_t)col0 * K + k0;
#pragma unroll
    for (int n = 0; n < BM / 64; n++) {
      int slot = n * 256 + tid;
      int seg = slot / BM, r = slot & (BM - 1);
      gload16(Ab + (size_t)r * K + seg * 8, &lA[buf][n * 2048 + wbase8]);
    }
#pragma unroll
    for (int n = 0; n < BN / 64; n++) {
      int slot = n * 256 + tid;
      int seg = slot / BN, r = slot & (BN - 1);
      gload16(Wb + (size_t)r * K + seg * 8, &lB[buf][n * 2048 + wbase8]);
    }
  };

  stage(0, 0);
  int buf = 0;
  for (int k0 = 0; k0 < K; k0 += 32) {
    __syncthreads();
    if (k0 + 32 < K) stage(buf ^ 1, k0 + 32);

    v8bf af[4], bfr[NJ];
#pragma unroll
    for (int i = 0; i < 4; i++)
      af[i] = load8(&lA[buf][(quad * BM + rw + i * 16 + l16) * 8]);
#pragma unroll
    for (int j = 0; j < NJ; j++)
      bfr[j] = load8(&lB[buf][(quad * BN + cw + j * 16 + l16) * 8]);
#pragma unroll
    for (int i = 0; i < 4; i++)
#pragma unroll
      for (int j = 0; j < NJ; j++)
        acc[i][j] = mfma16(af[i], bfr[j], acc[i][j]);
    buf ^= 1;
  }

#pragma unroll
  for (int i = 0; i < 4; i++) {
    int rbase = row0 + rw + i * 16 + quad * 4;
#pragma unroll
    for (int j = 0; j < NJ; j++) {
      int c = col0 + cw + j * 16 + l16;
      float bv = bias[c];
#pragma unroll
      for (int r = 0; r < 4; r++) {
        int tok = rbase + r;
        float v = acc[i][j][r] + bv;
        size_t idx = (size_t)tok * Nout + c;
        if (mode == 1) {
          out_bf[idx] = f2bf(res_f32[idx] + v);
        } else if (mode == 3) {
          out_f[idx] = bf2f(res_bf[idx]) + v;
        }
      }
    }
  }
}

// ---------------- big-tile GEMM engine (512 thr, 8 waves 2x4) ------------
// R13: 2-phase ceiling diagnosed. R10 (occupancy 2x: flat) + R12 (staged
// bytes /2: flat) killed both the latency and staging-BW models; all big
// GEMMs pin at ~300 TF = the per-K-step vmcnt(0)+barrier drain (guide
// m233: 72% of 2-phase time; our R3 proj: 4300 cyc/step vs 160 cyc MFMA).
// Fix = T3+T4 counted-vmcnt pipeline: 3 LDS buffers, raw s_barrier,
// s_waitcnt vmcnt(LOADS) so the newest stage's loads stay in flight
// ACROSS the barrier (never drain to 0 in-loop; m218: +38-73%).
// Safety: vmcnt is FIFO per wave (m135) and all waves issue symmetric
// stages, so vmcnt(LOADS)+barrier => oldest stage landed for ALL waves.
// A wave past the barrier has consumed its ds_reads (lgkm waits precede
// MFMA issue), so staging into the buffer it read LAST step is safe.
// LDS: 3*(BM+BN)*32*2B = 96KB (256^2) / 72KB (256x128) -> 1 blk/CU.
// mode 2: out_bf = gelu_fast(v)   mode 4: qkv head-major scatter
// mode 5: split-K=2 over blockIdx.z. z==0 -> bf16 raw partial in out_bf,
//         z==1 -> fp32 (v+bias+res_bf) in out_f; addred_kernel adds p0.
template <int BM, int BN>
__global__ __launch_bounds__(512, 2) void gemm_big_kernel(
    const u16* __restrict__ A, const u16* __restrict__ W,
    const float* __restrict__ bias, int K, int Nout, int mode,
    u16* __restrict__ out_bf, float* __restrict__ out_f,
    const u16* __restrict__ res_bf) {
  constexpr int NI = BM / 32;          // row fragments per wave (2 row-waves)
  constexpr int NJ = BN / 64;          // col fragments per wave (4 col-waves)
  constexpr int LOADS = BM / 128 + BN / 128;  // gload16 per thread per stage
  __shared__ alignas(16) u16 lA[3][BM * 32];  // [buf][seg][row][8]
  __shared__ alignas(16) u16 lB[3][BN * 32];  // [buf][seg][col][8]

  int tid = threadIdx.x;
  int lane = tid & 63, wid = tid >> 6;
  int quad = lane >> 4, l16 = lane & 15;
  int row0 = blockIdx.x * BM;
  int col0 = blockIdx.y * BN;
  int rw = (wid >> 2) * (BM / 2);
  int cw = (wid & 3) * (BN / 4);

  int kbeg = 0, kend = K;
  if (mode == 5) {
    int half = K >> 1;
    kbeg = blockIdx.z * half;
    kend = kbeg + half;
  }
  int nt = (kend - kbeg) >> 5;  // K-steps of 32

  v4f zero = {0.f, 0.f, 0.f, 0.f};
  v4f acc[NI][NJ];
#pragma unroll
  for (int i = 0; i < NI; i++)
#pragma unroll
    for (int j = 0; j < NJ; j++) acc[i][j] = zero;

  int wbase8 = (tid & 448) * 8;  // wave-uniform LDS slot base (u16 units)

  auto stage = [&](int buf, int k0) {
    const u16* Ab = A + (size_t)row0 * K + k0;
    const u16* Wb = W + (size_t)col0 * K + k0;
#pragma unroll
    for (int n = 0; n < BM / 128; n++) {
      int slot = n * 512 + tid;
      int seg = slot / BM, r = slot & (BM - 1);
      gload16(Ab + (size_t)r * K + seg * 8, &lA[buf][n * 4096 + wbase8]);
    }
#pragma unroll
    for (int n = 0; n < BN / 128; n++) {
      int slot = n * 512 + tid;
      int seg = slot / BN, r = slot & (BN - 1);
      gload16(Wb + (size_t)r * K + seg * 8, &lB[buf][n * 4096 + wbase8]);
    }
  };

  auto compute = [&](int bidx) {
    v8bf af[NI], bfr[NJ];
#pragma unroll
    for (int i = 0; i < NI; i++)
      af[i] = load8(&lA[bidx][(quad * BM + rw + i * 16 + l16) * 8]);
#pragma unroll
    for (int j = 0; j < NJ; j++)
      bfr[j] = load8(&lB[bidx][(quad * BN + cw + j * 16 + l16) * 8]);
#pragma unroll
    for (int i = 0; i < NI; i++)
#pragma unroll
      for (int j = 0; j < NJ; j++)
        acc[i][j] = mfma16(af[i], bfr[j], acc[i][j]);
  };

  // prologue: 2 stages in flight (pipeline depth 3 buffers / lookahead 2)
  stage(0, kbeg);
  stage(1, kbeg + 32);
  for (int t = 0; t < nt - 1; ++t) {
    waitcnt_vm<LOADS>();              // oldest stage landed; newest in flight
    __builtin_amdgcn_s_barrier();
    if (t + 2 < nt) stage((t + 2) % 3, kbeg + (t + 2) * 32);
    compute(t % 3);
  }
  // peeled final step: drain everything
  waitcnt_vm<0>();
  __builtin_amdgcn_s_barrier();
  compute((nt - 1) % 3);

#pragma unroll
  for (int i = 0; i < NI; i++) {
    int rbase = row0 + rw + i * 16 + quad * 4;
#pragma unroll
    for (int j = 0; j < NJ; j++) {
      int c = col0 + cw + j * 16 + l16;
      float bv = bias[c];
#pragma unroll
      for (int r = 0; r < 4; r++) {
        int tok = rbase + r;
        float raw = acc[i][j][r];
        float v = raw + bv;
        if (mode == 4) {
          int region = c >> 10;  // 0=q,1=k,2=v
          int cc = c & 1023;
          int hh = cc >> 6, dd = cc & 63;
          int l = tok >> 1, nn = tok & 1;
          size_t hb = (size_t)(nn * 16 + hh);
          if (region == 0) {
            out_bf[(hb * LSEQ + l) * 64 + dd] = f2bf(v * SCALING);
          } else if (region == 1) {
            out_bf[4194304 + (hb * LSEQ + l) * 64 + dd] = f2bf(v);
          } else {
            out_bf[8388608 + (hb * 64 + dd) * LSEQ + l] = f2bf(v);
          }
        } else {
          size_t idx = (size_t)tok * Nout + c;
          if (mode == 2) {
            out_bf[idx] = f2bf(gelu_fast(v));
          } else {  // mode 5: split-K partials
            if (blockIdx.z == 0) {
              out_bf[idx] = f2bf(raw);                  // chunk-0 raw partial
            } else {
              out_f[idx] = v + bf2f(res_bf[idx]);       // chunk-1 + bias + x2
            }
          }
        }
      }
    }
  }
}

// ---------------- Flash attention (no-max softmax, swizzled LDS) ---------
// Inputs head-major: q,k (n,h,l,d) [q pre-scaled], vt (n,h,d,l).
__global__ __launch_bounds__(256) void flash_kernel(
    const u16* __restrict__ qb, const u16* __restrict__ kb,
    const u16* __restrict__ vtb, u16* __restrict__ o) {
  int tid = threadIdx.x;
  int lane = tid & 63, wid = tid >> 6;
  int quad = lane >> 4, l16 = lane & 15;
  int qt = blockIdx.x;
  int nh = blockIdx.y;
  int n = nh >> 4, h = nh & 15;

  __shared__ alignas(16) u16 lK[4096];
  __shared__ alignas(16) u16 lV[4096];
  __shared__ alignas(16) u16 pl[128][72];

  const u16* khead = kb + (size_t)nh * (LSEQ * 64);
  const u16* vhead = vtb + (size_t)nh * (64 * LSEQ);

  v4f zero = {0.f, 0.f, 0.f, 0.f};
  v4f acc_o[2][4];
  float lsum[2][4];
#pragma unroll
  for (int i = 0; i < 2; i++) {
#pragma unroll
    for (int r = 0; r < 4; r++) lsum[i][r] = 0.f;
#pragma unroll
    for (int jd = 0; jd < 4; jd++) acc_o[i][jd] = zero;
  }

  v8bf qf[2][2];
#pragma unroll
  for (int i = 0; i < 2; i++) {
    int lq = qt * 128 + wid * 32 + i * 16 + l16;
#pragma unroll
    for (int kk = 0; kk < 2; kk++)
      qf[i][kk] = load8(qb + ((size_t)nh * LSEQ + lq) * 64 + kk * 32 + quad * 8);
  }

  int swl = l16 & 7;
  int srow = tid >> 3;
  int sseg0 = tid & 7;
  int lbase = (tid & 192) * 8;

  for (int s0 = 0; s0 < LSEQ; s0 += 64) {
#pragma unroll
    for (int p = 0; p < 2; p++) {
      int row = p * 32 + srow;
      int seg = sseg0 ^ (row & 7);
      gload16(khead + (size_t)(s0 + row) * 64 + seg * 8, &lK[p * 2048 + lbase]);
      gload16(vhead + (size_t)row * LSEQ + s0 + seg * 8, &lV[p * 2048 + lbase]);
    }
    __syncthreads();

    v4f sacc[2][4];
#pragma unroll
    for (int i = 0; i < 2; i++)
#pragma unroll
      for (int j = 0; j < 4; j++) sacc[i][j] = zero;
#pragma unroll
    for (int kk = 0; kk < 2; kk++) {
      v8bf kf[4];
#pragma unroll
      for (int j = 0; j < 4; j++) {
        int rl = j * 16 + l16;
        kf[j] = load8(&lK[((rl << 3) + (((kk << 2) + quad) ^ swl)) << 3]);
      }
#pragma unroll
      for (int i = 0; i < 2; i++)
#pragma unroll
        for (int j = 0; j < 4; j++)
          sacc[i][j] = mfma16(qf[i][kk], kf[j], sacc[i][j]);
    }

#pragma unroll
    for (int i = 0; i < 2; i++) {
#pragma unroll
      for (int r = 0; r < 4; r++) {
        float ps = 0.f;
#pragma unroll
        for (int j = 0; j < 4; j++) {
          float p = __expf(fminf(sacc[i][j][r], 60.f));
          ps += p;
          pl[wid * 32 + i * 16 + quad * 4 + r][j * 16 + l16] = f2bf(p);
        }
        lsum[i][r] += ps;
      }
    }

#pragma unroll
    for (int kk = 0; kk < 2; kk++) {
      v8bf pf[2], vf[4];
#pragma unroll
      for (int i = 0; i < 2; i++)
        pf[i] = load8(&pl[wid * 32 + i * 16 + l16][kk * 32 + quad * 8]);
#pragma unroll
      for (int jd = 0; jd < 4; jd++) {
        int dl = jd * 16 + l16;
        vf[jd] = load8(&lV[((dl << 3) + (((kk << 2) + quad) ^ swl)) << 3]);
      }
#pragma unroll
      for (int i = 0; i < 2; i++)
#pragma unroll
        for (int jd = 0; jd < 4; jd++)
          acc_o[i][jd] = mfma16(pf[i], vf[jd], acc_o[i][jd]);
    }
    __syncthreads();
  }

#pragma unroll
  for (int i = 0; i < 2; i++) {
#pragma unroll
    for (int r = 0; r < 4; r++) {
      float s = lsum[i][r];
#pragma unroll
      for (int off = 1; off < 16; off <<= 1) s += __shfl_xor(s, off);
      float inv = 1.0f / s;
      int lq = qt * 128 + wid * 32 + i * 16 + quad * 4 + r;
      size_t t = (size_t)lq * NBATCH + n;
#pragma unroll
      for (int jd = 0; jd < 4; jd++)
        o[t * EMB + h * 64 + jd * 16 + l16] = f2bf(acc_o[i][jd][r] * inv);
    }
  }
}

// ---------------- launcher ----------------
extern "C" void kernel_launch(void* const* d_in, const int* in_sizes, int n_in,
                              void* d_out, int out_size, void* d_ws,
                              size_t ws_size, hipStream_t stream) {
  const float* x = (const float*)d_in[0];
  const float* ln1_w = (const float*)d_in[1];
  const float* ln1_b = (const float*)d_in[2];
  const float* in_proj_w = (const float*)d_in[3];
  const float* in_proj_b = (const float*)d_in[4];
  const float* out_w = (const float*)d_in[5];
  const float* out_b = (const float*)d_in[6];
  const float* ln2_w = (const float*)d_in[7];
  const float* ln2_b = (const float*)d_in[8];
  const float* fc_w = (const float*)d_in[9];
  const float* fc_b = (const float*)d_in[10];
  const float* proj_w = (const float*)d_in[11];
  const float* proj_b = (const float*)d_in[12];
  float* out = (float*)d_out;

  char* ws = (char*)d_ws;
  // wbuf [0,8) ; y/o/h [8,40) ; qkv head-major [16,40) ; x2 bf16 [40,48) ;
  // z [48,56).  56 MB peak (known-good budget).
  u16* wbuf = (u16*)(ws + 0);
  u16* y = (u16*)(ws + 8388608);
  u16* qkvh = (u16*)(ws + 16777216);
  u16* o = (u16*)(ws + 8388608);
  u16* hbuf = (u16*)(ws + 8388608);
  u16* x2 = (u16*)(ws + 41943040);
  u16* z = (u16*)(ws + 50331648);

  u16* qb = qkvh;
  u16* kb = qkvh + 4194304;
  u16* vtb = qkvh + 8388608;

  // 1. ln1(x) -> y
  ln_kernel<1><<<TOK, 256, 0, stream>>>((const void*)x, ln1_w, ln1_b, y);
  // 2. qkv = y @ in_proj^T + b, head-major scatter (q scaled). Grid (16,12).
  cvt_kernel<<<1536, 256, 0, stream>>>(in_proj_w, wbuf);
  gemm_big_kernel<256, 256><<<dim3(16, 12), 512, 0, stream>>>(
      y, wbuf, in_proj_b, EMB, 3 * EMB, 4, qkvh, nullptr, nullptr);
  // 3. attention -> o
  flash_kernel<<<dim3(16, 32), 256, 0, stream>>>(qb, kb, vtb, o);
  // 4. x2 = bf16(x + o @ out_w^T + out_b). Small GEMM, unchanged.
  cvt_kernel<<<512, 256, 0, stream>>>(out_w, wbuf);
  gemm_db_kernel<64, 128><<<dim3(64, 8), 256, 0, stream>>>(
      o, wbuf, out_b, EMB, EMB, 1, x2, nullptr, x, nullptr);
  // 5. ln2(x2) -> z
  ln_kernel<0><<<TOK, 256, 0, stream>>>((const void*)x2, ln2_w, ln2_b, z);
  // 6. h = gelu_fast(z @ fc_w^T + fc_b). Grid (16,16).
  cvt_kernel<<<2048, 256, 0, stream>>>(fc_w, wbuf);
  gemm_big_kernel<256, 256><<<dim3(16, 16), 512, 0, stream>>>(
      z, wbuf, fc_b, EMB, 4 * EMB, 2, hbuf, nullptr, nullptr);
  // 7. out = x2 + h @ proj_w^T + proj_b. 256x128 sk2, grid (16,8,2).
  //    Chunk0 -> bf16 partial in z; chunk1 (+bias+x2) -> fp32 d_out;
  //    addred does out += p0.
  cvt_kernel<<<2048, 256, 0, stream>>>(proj_w, wbuf);
  gemm_big_kernel<256, 128><<<dim3(16, 8, 2), 512, 0, stream>>>(
      hbuf, wbuf, proj_b, 4 * EMB, EMB, 5, z, out, x2);
  addred_kernel<<<2048, 256, 0, stream>>>(out, z);
}

// Round 5
// 462.704 us; speedup vs baseline: 1.1460x; 1.1392x over previous
//
#include <hip/hip_runtime.h>
#include <hip/hip_bf16.h>

typedef unsigned short u16;
typedef float v4f __attribute__((ext_vector_type(4)));
typedef __bf16 v8bf __attribute__((ext_vector_type(8)));
typedef unsigned short v4u __attribute__((ext_vector_type(4)));
typedef unsigned short v8u __attribute__((ext_vector_type(8)));

#define EMB 1024
#define TOK 4096
#define LSEQ 2048
#define NBATCH 2
#define SCALING 0.015625f
#define LN_EPS 1e-5f

__device__ __forceinline__ float bf2f(u16 u) {
  unsigned int i = ((unsigned int)u) << 16;
  return __builtin_bit_cast(float, i);
}
__device__ __forceinline__ u16 f2bf(float f) {
  __hip_bfloat16 h = __float2bfloat16(f);  // RNE
  return __builtin_bit_cast(u16, h);
}
__device__ __forceinline__ v8bf load8(const u16* p) {
  return *reinterpret_cast<const v8bf*>(p);
}
__device__ __forceinline__ v4f mfma16(v8bf a, v8bf b, v4f c) {
  return __builtin_amdgcn_mfma_f32_16x16x32_bf16(a, b, c, 0, 0, 0);
}
// async global->LDS, 16B/lane; LDS dest = wave-uniform base + lane*16
__device__ __forceinline__ void gload16(const u16* g, u16* l) {
  __builtin_amdgcn_global_load_lds(
      (const __attribute__((address_space(1))) void*)g,
      (__attribute__((address_space(3))) void*)l, 16, 0, 0);
}
// counted vmcnt wait: allow N loads to remain in flight (T4)
template <int N>
__device__ __forceinline__ void waitcnt_vm() {
  if constexpr (N == 0) asm volatile("s_waitcnt vmcnt(0)" ::: "memory");
  else if constexpr (N == 2) asm volatile("s_waitcnt vmcnt(2)" ::: "memory");
  else if constexpr (N == 3) asm volatile("s_waitcnt vmcnt(3)" ::: "memory");
  else if constexpr (N == 4) asm volatile("s_waitcnt vmcnt(4)" ::: "memory");
  else if constexpr (N == 6) asm volatile("s_waitcnt vmcnt(6)" ::: "memory");
  else if constexpr (N == 8) asm volatile("s_waitcnt vmcnt(8)" ::: "memory");
}
// fast GELU (tanh form, ~9 VALU ops, no divergence): max |err| ~3e-4
__device__ __forceinline__ float gelu_fast(float v) {
  float u = v * (0.7978845608f + 0.0356774081f * v * v);
  return v / (1.0f + __expf(-2.0f * u));
}

// ---------------- fp32 -> bf16 weight conversion -------------------------
__global__ __launch_bounds__(256) void cvt_kernel(
    const float* __restrict__ in, u16* __restrict__ out) {
  size_t i = ((size_t)blockIdx.x * 256 + threadIdx.x) * 8;
  v4f a = *reinterpret_cast<const v4f*>(in + i);
  v4f b = *reinterpret_cast<const v4f*>(in + i + 4);
  v8u r;
#pragma unroll
  for (int j = 0; j < 4; j++) { r[j] = f2bf(a[j]); r[4 + j] = f2bf(b[j]); }
  *reinterpret_cast<v8u*>(out + i) = r;
}

// ---------------- split-K reduce: out += p0(bf16) ------------------------
__global__ __launch_bounds__(256) void addred_kernel(
    float* __restrict__ out, const u16* __restrict__ p0) {
  size_t i = ((size_t)blockIdx.x * 256 + threadIdx.x) * 8;
  v4f a0 = *reinterpret_cast<const v4f*>(out + i);
  v4f a1 = *reinterpret_cast<const v4f*>(out + i + 4);
  v8u pp = *reinterpret_cast<const v8u*>(p0 + i);
#pragma unroll
  for (int j = 0; j < 4; j++) {
    a0[j] += bf2f(pp[j]);
    a1[j] += bf2f(pp[4 + j]);
  }
  *reinterpret_cast<v4f*>(out + i) = a0;
  *reinterpret_cast<v4f*>(out + i + 4) = a1;
}

// ---------------- LayerNorm: MODE 0 bf16-in, MODE 1 fp32-in -> bf16 out --
template <int MODE>
__global__ __launch_bounds__(256) void ln_kernel(
    const void* __restrict__ xin, const float* __restrict__ w,
    const float* __restrict__ b, u16* __restrict__ y) {
  int t = blockIdx.x, tid = threadIdx.x;
  float v[4];
  if (MODE == 0) {
    v4u raw = *reinterpret_cast<const v4u*>((const u16*)xin + (size_t)t * EMB + tid * 4);
#pragma unroll
    for (int j = 0; j < 4; j++) v[j] = bf2f(raw[j]);
  } else {
    v4f raw = *reinterpret_cast<const v4f*>((const float*)xin + (size_t)t * EMB + tid * 4);
#pragma unroll
    for (int j = 0; j < 4; j++) v[j] = raw[j];
  }
  float s = v[0] + v[1] + v[2] + v[3];
  float ss = v[0] * v[0] + v[1] * v[1] + v[2] * v[2] + v[3] * v[3];
#pragma unroll
  for (int off = 32; off >= 1; off >>= 1) {
    s += __shfl_xor(s, off);
    ss += __shfl_xor(ss, off);
  }
  __shared__ float sm[4], sq[4];
  if ((tid & 63) == 0) { sm[tid >> 6] = s; sq[tid >> 6] = ss; }
  __syncthreads();
  s = sm[0] + sm[1] + sm[2] + sm[3];
  ss = sq[0] + sq[1] + sq[2] + sq[3];
  float mu = s * (1.0f / EMB);
  float var = ss * (1.0f / EMB) - mu * mu;
  float rstd = rsqrtf(var + LN_EPS);
  v4f wv = *reinterpret_cast<const v4f*>(w + tid * 4);
  v4f bv = *reinterpret_cast<const v4f*>(b + tid * 4);
  v4u out;
#pragma unroll
  for (int j = 0; j < 4; j++) out[j] = f2bf((v[j] - mu) * rstd * wv[j] + bv[j]);
  *reinterpret_cast<v4u*>(y + (size_t)t * EMB + tid * 4) = out;
}

// ---------------- small GEMM engine (256 thr, <64,128>): out GEMM only ---
// R14 CONTROL: left on the scattered [seg][row] staging on purpose — if
// the big GEMMs speed up and this one doesn't, the request-rate model is
// confirmed.  mode 1: out_bf = bf16(res_f32 + v)
template <int BM, int BN>
__global__ __launch_bounds__(256) void gemm_db_kernel(
    const u16* __restrict__ A, const u16* __restrict__ W,
    const float* __restrict__ bias, int K, int Nout, int mode,
    u16* __restrict__ out_bf, float* __restrict__ out_f,
    const float* __restrict__ res_f32, const u16* __restrict__ res_bf) {
  constexpr int NJ = BM * BN / 4096;   // col fragments per wave
  constexpr int CWV = 4 / (BM / 64);   // col-waves
  __shared__ alignas(16) u16 lA[2][BM * 32];  // [buf][seg][row][8]
  __shared__ alignas(16) u16 lB[2][BN * 32];  // [buf][seg][col][8]

  int tid = threadIdx.x;
  int lane = tid & 63, wid = tid >> 6;
  int quad = lane >> 4, l16 = lane & 15;
  int row0 = blockIdx.x * BM;
  int col0 = blockIdx.y * BN;
  int rw = (wid / CWV) * 64;
  int cw = (wid % CWV) * (BN / CWV);

  v4f zero = {0.f, 0.f, 0.f, 0.f};
  v4f acc[4][NJ];
#pragma unroll
  for (int i = 0; i < 4; i++)
#pragma unroll
    for (int j = 0; j < NJ; j++) acc[i][j] = zero;

  int wbase8 = (tid & 192) * 8;  // wave-uniform LDS slot base (u16 units)

  auto stage = [&](int buf, int k0) {
    const u16* Ab = A + (size_t)row0 * K + k0;
    const u16* Wb = W + (size_t)col0 * K + k0;
#pragma unroll
    for (int n = 0; n < BM / 64; n++) {
      int slot = n * 256 + tid;
      int seg = slot / BM, r = slot & (BM - 1);
      gload16(Ab + (size_t)r * K + seg * 8, &lA[buf][n * 2048 + wbase8]);
    }
#pragma unroll
    for (int n = 0; n < BN / 64; n++) {
      int slot = n * 256 + tid;
      int seg = slot / BN, r = slot & (BN - 1);
      gload16(Wb + (size_t)r * K + seg * 8, &lB[buf][n * 2048 + wbase8]);
    }
  };

  stage(0, 0);
  int buf = 0;
  for (int k0 = 0; k0 < K; k0 += 32) {
    __syncthreads();
    if (k0 + 32 < K) stage(buf ^ 1, k0 + 32);

    v8bf af[4], bfr[NJ];
#pragma unroll
    for (int i = 0; i < 4; i++)
      af[i] = load8(&lA[buf][(quad * BM + rw + i * 16 + l16) * 8]);
#pragma unroll
    for (int j = 0; j < NJ; j++)
      bfr[j] = load8(&lB[buf][(quad * BN + cw + j * 16 + l16) * 8]);
#pragma unroll
    for (int i = 0; i < 4; i++)
#pragma unroll
      for (int j = 0; j < NJ; j++)
        acc[i][j] = mfma16(af[i], bfr[j], acc[i][j]);
    buf ^= 1;
  }

#pragma unroll
  for (int i = 0; i < 4; i++) {
    int rbase = row0 + rw + i * 16 + quad * 4;
#pragma unroll
    for (int j = 0; j < NJ; j++) {
      int c = col0 + cw + j * 16 + l16;
      float bv = bias[c];
#pragma unroll
      for (int r = 0; r < 4; r++) {
        int tok = rbase + r;
        float v = acc[i][j][r] + bv;
        size_t idx = (size_t)tok * Nout + c;
        if (mode == 1) {
          out_bf[idx] = f2bf(res_f32[idx] + v);
        } else if (mode == 3) {
          out_f[idx] = bf2f(res_bf[idx]) + v;
        }
      }
    }
  }
}

// ---------------- big-tile GEMM engine (512 thr, 8 waves 2x4) ------------
// R14: request-rate model. R1 (occ x2), R3 (staged bytes /2), R4 (counted
// vmcnt 3-buf) were ALL flat at ~110 µs -> the shared invariant was the
// [seg][row] staging: lane i reads row i -> 64 lanes = 64 distinct 2KB-
// apart cache lines, 16B used per request. Measured request rates: R4 proj
// 0.37 req/cyc/CU, R2 fc 0.5, m97 (13 TB/s staging) 0.33 at 64B/req ->
// per-CU L2 request rate caps ~0.4-0.5/cyc; bytes/request is the lever.
// Fix: row-major LDS [row][seg] so 4 consecutive lanes read one full 64B
// line (16 lines/wave-instr, was 64). ds_read 16-way bank conflict that
// this layout would cause is killed by rule-21 both-sides XOR swizzle:
//   phys_seg = seg ^ ((row>>1)&3)
// applied to the GLOBAL source (permutes within the same 64B line -> still
// coalesced) and to the ds_read address. 8 consecutive rows cover all 8
// 16B-slots mod 128B -> 2-way only (free, m136).
// Schedule: R4's 3-buffer counted-vmcnt kept (never drain in-loop).
// mode 2: out_bf = gelu_fast(v)   mode 4: qkv head-major scatter
// mode 5: split-K=2 over blockIdx.z. z==0 -> bf16 raw partial in out_bf,
//         z==1 -> fp32 (v+bias+res_bf) in out_f; addred_kernel adds p0.
template <int BM, int BN>
__global__ __launch_bounds__(512, 2) void gemm_big_kernel(
    const u16* __restrict__ A, const u16* __restrict__ W,
    const float* __restrict__ bias, int K, int Nout, int mode,
    u16* __restrict__ out_bf, float* __restrict__ out_f,
    const u16* __restrict__ res_bf) {
  constexpr int NI = BM / 32;          // row fragments per wave (2 row-waves)
  constexpr int NJ = BN / 64;          // col fragments per wave (4 col-waves)
  constexpr int LOADS = BM / 128 + BN / 128;  // gload16 per thread per stage
  __shared__ alignas(16) u16 lA[3][BM * 32];  // [buf][row][phys_seg][8]
  __shared__ alignas(16) u16 lB[3][BN * 32];  // [buf][col][phys_seg][8]

  int tid = threadIdx.x;
  int lane = tid & 63, wid = tid >> 6;
  int quad = lane >> 4, l16 = lane & 15;
  int row0 = blockIdx.x * BM;
  int col0 = blockIdx.y * BN;
  int rw = (wid >> 2) * (BM / 2);
  int cw = (wid & 3) * (BN / 4);

  int kbeg = 0, kend = K;
  if (mode == 5) {
    int half = K >> 1;
    kbeg = blockIdx.z * half;
    kend = kbeg + half;
  }
  int nt = (kend - kbeg) >> 5;  // K-steps of 32

  v4f zero = {0.f, 0.f, 0.f, 0.f};
  v4f acc[NI][NJ];
#pragma unroll
  for (int i = 0; i < NI; i++)
#pragma unroll
    for (int j = 0; j < NJ; j++) acc[i][j] = zero;

  int wbase8 = (tid & 448) * 8;  // wave-uniform LDS slot base (u16 units)

  auto stage = [&](int buf, int k0) {
    const u16* Ab = A + (size_t)row0 * K + k0;
    const u16* Wb = W + (size_t)col0 * K + k0;
    // phys slot p = r*4 + sp holds logical seg sl = sp ^ ((r>>1)&3).
    // Lanes 0..3 share row r=p>>2 -> one 64B line (permuted within line).
#pragma unroll
    for (int n = 0; n < BM / 128; n++) {
      int p = n * 512 + tid;
      int r = p >> 2, sp = p & 3;
      int sl = sp ^ ((r >> 1) & 3);
      gload16(Ab + (size_t)r * K + sl * 8, &lA[buf][n * 4096 + wbase8]);
    }
#pragma unroll
    for (int n = 0; n < BN / 128; n++) {
      int p = n * 512 + tid;
      int r = p >> 2, sp = p & 3;
      int sl = sp ^ ((r >> 1) & 3);
      gload16(Wb + (size_t)r * K + sl * 8, &lB[buf][n * 4096 + wbase8]);
    }
  };

  auto compute = [&](int bidx) {
    v8bf af[NI], bfr[NJ];
#pragma unroll
    for (int i = 0; i < NI; i++) {
      int ra = rw + i * 16 + l16;
      af[i] = load8(&lA[bidx][((ra << 2) + (quad ^ ((ra >> 1) & 3))) << 3]);
    }
#pragma unroll
    for (int j = 0; j < NJ; j++) {
      int rb = cw + j * 16 + l16;
      bfr[j] = load8(&lB[bidx][((rb << 2) + (quad ^ ((rb >> 1) & 3))) << 3]);
    }
#pragma unroll
    for (int i = 0; i < NI; i++)
#pragma unroll
      for (int j = 0; j < NJ; j++)
        acc[i][j] = mfma16(af[i], bfr[j], acc[i][j]);
  };

  // prologue: 2 stages in flight (3 buffers / lookahead 2)
  stage(0, kbeg);
  stage(1, kbeg + 32);
  for (int t = 0; t < nt - 1; ++t) {
    waitcnt_vm<LOADS>();              // oldest stage landed; newest in flight
    __builtin_amdgcn_s_barrier();
    if (t + 2 < nt) stage((t + 2) % 3, kbeg + (t + 2) * 32);
    compute(t % 3);
  }
  // peeled final step: drain everything
  waitcnt_vm<0>();
  __builtin_amdgcn_s_barrier();
  compute((nt - 1) % 3);

#pragma unroll
  for (int i = 0; i < NI; i++) {
    int rbase = row0 + rw + i * 16 + quad * 4;
#pragma unroll
    for (int j = 0; j < NJ; j++) {
      int c = col0 + cw + j * 16 + l16;
      float bv = bias[c];
#pragma unroll
      for (int r = 0; r < 4; r++) {
        int tok = rbase + r;
        float raw = acc[i][j][r];
        float v = raw + bv;
        if (mode == 4) {
          int region = c >> 10;  // 0=q,1=k,2=v
          int cc = c & 1023;
          int hh = cc >> 6, dd = cc & 63;
          int l = tok >> 1, nn = tok & 1;
          size_t hb = (size_t)(nn * 16 + hh);
          if (region == 0) {
            out_bf[(hb * LSEQ + l) * 64 + dd] = f2bf(v * SCALING);
          } else if (region == 1) {
            out_bf[4194304 + (hb * LSEQ + l) * 64 + dd] = f2bf(v);
          } else {
            out_bf[8388608 + (hb * 64 + dd) * LSEQ + l] = f2bf(v);
          }
        } else {
          size_t idx = (size_t)tok * Nout + c;
          if (mode == 2) {
            out_bf[idx] = f2bf(gelu_fast(v));
          } else {  // mode 5: split-K partials
            if (blockIdx.z == 0) {
              out_bf[idx] = f2bf(raw);                  // chunk-0 raw partial
            } else {
              out_f[idx] = v + bf2f(res_bf[idx]);       // chunk-1 + bias + x2
            }
          }
        }
      }
    }
  }
}

// ---------------- Flash attention (no-max softmax, swizzled LDS) ---------
// Inputs head-major: q,k (n,h,l,d) [q pre-scaled], vt (n,h,d,l).
// Staging already coalesced: 8 lanes cover one 128B row.
__global__ __launch_bounds__(256) void flash_kernel(
    const u16* __restrict__ qb, const u16* __restrict__ kb,
    const u16* __restrict__ vtb, u16* __restrict__ o) {
  int tid = threadIdx.x;
  int lane = tid & 63, wid = tid >> 6;
  int quad = lane >> 4, l16 = lane & 15;
  int qt = blockIdx.x;
  int nh = blockIdx.y;
  int n = nh >> 4, h = nh & 15;

  __shared__ alignas(16) u16 lK[4096];
  __shared__ alignas(16) u16 lV[4096];
  __shared__ alignas(16) u16 pl[128][72];

  const u16* khead = kb + (size_t)nh * (LSEQ * 64);
  const u16* vhead = vtb + (size_t)nh * (64 * LSEQ);

  v4f zero = {0.f, 0.f, 0.f, 0.f};
  v4f acc_o[2][4];
  float lsum[2][4];
#pragma unroll
  for (int i = 0; i < 2; i++) {
#pragma unroll
    for (int r = 0; r < 4; r++) lsum[i][r] = 0.f;
#pragma unroll
    for (int jd = 0; jd < 4; jd++) acc_o[i][jd] = zero;
  }

  v8bf qf[2][2];
#pragma unroll
  for (int i = 0; i < 2; i++) {
    int lq = qt * 128 + wid * 32 + i * 16 + l16;
#pragma unroll
    for (int kk = 0; kk < 2; kk++)
      qf[i][kk] = load8(qb + ((size_t)nh * LSEQ + lq) * 64 + kk * 32 + quad * 8);
  }

  int swl = l16 & 7;
  int srow = tid >> 3;
  int sseg0 = tid & 7;
  int lbase = (tid & 192) * 8;

  for (int s0 = 0; s0 < LSEQ; s0 += 64) {
#pragma unroll
    for (int p = 0; p < 2; p++) {
      int row = p * 32 + srow;
      int seg = sseg0 ^ (row & 7);
      gload16(khead + (size_t)(s0 + row) * 64 + seg * 8, &lK[p * 2048 + lbase]);
      gload16(vhead + (size_t)row * LSEQ + s0 + seg * 8, &lV[p * 2048 + lbase]);
    }
    __syncthreads();

    v4f sacc[2][4];
#pragma unroll
    for (int i = 0; i < 2; i++)
#pragma unroll
      for (int j = 0; j < 4; j++) sacc[i][j] = zero;
#pragma unroll
    for (int kk = 0; kk < 2; kk++) {
      v8bf kf[4];
#pragma unroll
      for (int j = 0; j < 4; j++) {
        int rl = j * 16 + l16;
        kf[j] = load8(&lK[((rl << 3) + (((kk << 2) + quad) ^ swl)) << 3]);
      }
#pragma unroll
      for (int i = 0; i < 2; i++)
#pragma unroll
        for (int j = 0; j < 4; j++)
          sacc[i][j] = mfma16(qf[i][kk], kf[j], sacc[i][j]);
    }

#pragma unroll
    for (int i = 0; i < 2; i++) {
#pragma unroll
      for (int r = 0; r < 4; r++) {
        float ps = 0.f;
#pragma unroll
        for (int j = 0; j < 4; j++) {
          float p = __expf(fminf(sacc[i][j][r], 60.f));
          ps += p;
          pl[wid * 32 + i * 16 + quad * 4 + r][j * 16 + l16] = f2bf(p);
        }
        lsum[i][r] += ps;
      }
    }

#pragma unroll
    for (int kk = 0; kk < 2; kk++) {
      v8bf pf[2], vf[4];
#pragma unroll
      for (int i = 0; i < 2; i++)
        pf[i] = load8(&pl[wid * 32 + i * 16 + l16][kk * 32 + quad * 8]);
#pragma unroll
      for (int jd = 0; jd < 4; jd++) {
        int dl = jd * 16 + l16;
        vf[jd] = load8(&lV[((dl << 3) + (((kk << 2) + quad) ^ swl)) << 3]);
      }
#pragma unroll
      for (int i = 0; i < 2; i++)
#pragma unroll
        for (int jd = 0; jd < 4; jd++)
          acc_o[i][jd] = mfma16(pf[i], vf[jd], acc_o[i][jd]);
    }
    __syncthreads();
  }

#pragma unroll
  for (int i = 0; i < 2; i++) {
#pragma unroll
    for (int r = 0; r < 4; r++) {
      float s = lsum[i][r];
#pragma unroll
      for (int off = 1; off < 16; off <<= 1) s += __shfl_xor(s, off);
      float inv = 1.0f / s;
      int lq = qt * 128 + wid * 32 + i * 16 + quad * 4 + r;
      size_t t = (size_t)lq * NBATCH + n;
#pragma unroll
      for (int jd = 0; jd < 4; jd++)
        o[t * EMB + h * 64 + jd * 16 + l16] = f2bf(acc_o[i][jd][r] * inv);
    }
  }
}

// ---------------- launcher ----------------
extern "C" void kernel_launch(void* const* d_in, const int* in_sizes, int n_in,
                              void* d_out, int out_size, void* d_ws,
                              size_t ws_size, hipStream_t stream) {
  const float* x = (const float*)d_in[0];
  const float* ln1_w = (const float*)d_in[1];
  const float* ln1_b = (const float*)d_in[2];
  const float* in_proj_w = (const float*)d_in[3];
  const float* in_proj_b = (const float*)d_in[4];
  const float* out_w = (const float*)d_in[5];
  const float* out_b = (const float*)d_in[6];
  const float* ln2_w = (const float*)d_in[7];
  const float* ln2_b = (const float*)d_in[8];
  const float* fc_w = (const float*)d_in[9];
  const float* fc_b = (const float*)d_in[10];
  const float* proj_w = (const float*)d_in[11];
  const float* proj_b = (const float*)d_in[12];
  float* out = (float*)d_out;

  char* ws = (char*)d_ws;
  // wbuf [0,8) ; y/o/h [8,40) ; qkv head-major [16,40) ; x2 bf16 [40,48) ;
  // z [48,56).  56 MB peak (known-good budget).
  u16* wbuf = (u16*)(ws + 0);
  u16* y = (u16*)(ws + 8388608);
  u16* qkvh = (u16*)(ws + 16777216);
  u16* o = (u16*)(ws + 8388608);
  u16* hbuf = (u16*)(ws + 8388608);
  u16* x2 = (u16*)(ws + 41943040);
  u16* z = (u16*)(ws + 50331648);

  u16* qb = qkvh;
  u16* kb = qkvh + 4194304;
  u16* vtb = qkvh + 8388608;

  // 1. ln1(x) -> y
  ln_kernel<1><<<TOK, 256, 0, stream>>>((const void*)x, ln1_w, ln1_b, y);
  // 2. qkv = y @ in_proj^T + b, head-major scatter (q scaled). Grid (16,12).
  cvt_kernel<<<1536, 256, 0, stream>>>(in_proj_w, wbuf);
  gemm_big_kernel<256, 256><<<dim3(16, 12), 512, 0, stream>>>(
      y, wbuf, in_proj_b, EMB, 3 * EMB, 4, qkvh, nullptr, nullptr);
  // 3. attention -> o
  flash_kernel<<<dim3(16, 32), 256, 0, stream>>>(qb, kb, vtb, o);
  // 4. x2 = bf16(x + o @ out_w^T + out_b). Small GEMM, CONTROL (scattered).
  cvt_kernel<<<512, 256, 0, stream>>>(out_w, wbuf);
  gemm_db_kernel<64, 128><<<dim3(64, 8), 256, 0, stream>>>(
      o, wbuf, out_b, EMB, EMB, 1, x2, nullptr, x, nullptr);
  // 5. ln2(x2) -> z
  ln_kernel<0><<<TOK, 256, 0, stream>>>((const void*)x2, ln2_w, ln2_b, z);
  // 6. h = gelu_fast(z @ fc_w^T + fc_b). Grid (16,16).
  cvt_kernel<<<2048, 256, 0, stream>>>(fc_w, wbuf);
  gemm_big_kernel<256, 256><<<dim3(16, 16), 512, 0, stream>>>(
      z, wbuf, fc_b, EMB, 4 * EMB, 2, hbuf, nullptr, nullptr);
  // 7. out = x2 + h @ proj_w^T + proj_b. 256x128 sk2, grid (16,8,2).
  //    Chunk0 -> bf16 partial in z; chunk1 (+bias+x2) -> fp32 d_out;
  //    addred does out += p0.
  cvt_kernel<<<2048, 256, 0, stream>>>(proj_w, wbuf);
  gemm_big_kernel<256, 128><<<dim3(16, 8, 2), 512, 0, stream>>>(
      hbuf, wbuf, proj_b, 4 * EMB, EMB, 5, z, out, x2);
  addred_kernel<<<2048, 256, 0, stream>>>(out, z);
}